// Round 1
// 704.926 us; speedup vs baseline: 1.4546x; 1.4546x over previous
//
#include <hip/hip_runtime.h>
#include <hip/hip_bf16.h>
#include <cstddef>

// Problem constants
#define BB    8
#define CIN   64
#define HH    256
#define WW    256
#define NN    65536            // H*W per batch
#define NP    (BB*NN)          // total pixels = 524288
#define QC    64               // q channels = HEADS*QD
#define KC    16               // k channels = QD*U
#define VC    32               // v channels = VD*U
#define HEADS 4
#define QD    16

// fp32 scratch (float-element offsets within ws)
#define WALL_OFF 0             // 112x64 BN-folded [Wq(0-63); Wk(64-79); Wv(80-111)]
#define BQ_OFF 7168            // 64
#define BV_OFF 7232            // 32
#define WP_OFF 7264            // 16*9
#define BP_OFF 7408            // 16
#define S_OFF  7424            // B*KC softmax denominators
#define M_OFF  7552            // B*KC*VC numerators
#define SMALL_END 11648
#define FLAG_OFF 12000         // int flag: 1 = inputs are fp32, 0 = bf16
#define BF_BASE 65536          // byte offset where bf16 staging starts

typedef __hip_bfloat16 bf16;
typedef __attribute__((ext_vector_type(8))) short short8;  // 8 bf16 (4 VGPRs)
typedef __attribute__((ext_vector_type(4))) float f32x4;   // MFMA C/D

__device__ __forceinline__ short f2bf_s(float f) {
    bf16 h = (bf16)f;
    return __builtin_bit_cast(short, h);
}

// Inline-asm MFMA (avoids builtin-signature ambiguity; hazards guarded at call
// sites with sched_barrier(0) + s_nop since the recognizer can't see into asm).
__device__ __forceinline__ f32x4 mfma_init(short8 a, short8 b, f32x4 c) {
    f32x4 d;
    asm("v_mfma_f32_16x16x32_bf16 %0, %1, %2, %3"
        : "=&v"(d) : "v"(a), "v"(b), "v"(c));
    return d;
}
__device__ __forceinline__ void mfma_acc(short8 a, short8 b, f32x4& c) {
    asm("v_mfma_f32_16x16x32_bf16 %0, %1, %2, %0"
        : "+v"(c) : "v"(a), "v"(b));
}

// ---------------- K-1: detect input dtype --------------------------------
__global__ void k_detect(const unsigned short* __restrict xu, int* __restrict flag) {
    if (threadIdx.x == 0 && blockIdx.x == 0) {
        int big = 0, zero = 0;
        for (int i = 0; i < 256; ++i) {
            unsigned short u = xu[i];
            int e = (u >> 7) & 0xFF;
            big  += (e >= 134);
            zero += (u == 0);
        }
        *flag = (big > 4 || zero > 64) ? 1 : 0;
    }
}

__device__ __forceinline__ float ldin(const void* p, int i, int isf) {
    return isf ? ((const float*)p)[i] : (float)(((const bf16*)p)[i]);
}

// ---------------- K0: weight prep (convert to fp32, fold BN) + zero S/M ----
// New layout: one contiguous 112x64 row-major W so k_qkv's MFMA A-fragments
// index a single matrix: rows 0-63 = Wq*BN, 64-79 = Wk, 80-111 = Wv*BN.
__global__ void k_prep(const void* __restrict wq, const void* __restrict gq,
                       const void* __restrict bq, const void* __restrict wk,
                       const void* __restrict wv, const void* __restrict gv,
                       const void* __restrict bv, const void* __restrict wp,
                       const void* __restrict bp, float* __restrict wf,
                       const int* __restrict flag) {
    int t = threadIdx.x;
    int isf = *flag;
    float rs = rsqrtf(1.0f + 1e-5f);
    for (int i = t; i < 4096; i += 256)
        wf[WALL_OFF + i] = ldin(wq, i, isf) * (ldin(gq, i>>6, isf) * rs);
    for (int i = t; i < 1024; i += 256)
        wf[WALL_OFF + 4096 + i] = ldin(wk, i, isf);
    for (int i = t; i < 2048; i += 256)
        wf[WALL_OFF + 5120 + i] = ldin(wv, i, isf) * (ldin(gv, i>>6, isf) * rs);
    for (int i = t; i < 64;   i += 256) wf[BQ_OFF+i] = ldin(bq, i, isf);
    for (int i = t; i < 32;   i += 256) wf[BV_OFF+i] = ldin(bv, i, isf);
    for (int i = t; i < 144;  i += 256) wf[WP_OFF+i] = ldin(wp, i, isf);
    for (int i = t; i < 16;   i += 256) wf[BP_OFF+i] = ldin(bp, i, isf);
    for (int i = t; i < SMALL_END - S_OFF; i += 256) wf[S_OFF + i] = 0.0f;  // zero S,M
}

// ---------------- K1: q / exp(k) / v via MFMA ------------------------------
// GEMM: out[112][p] = W[112][64] * x[64][p], per batch. One wave owns 4
// N-tiles of 16 pixels. A (weights) preloaded in VGPRs; B (x) loaded straight
// from global in fragment order (16-lane 64B runs); no LDS.
#define TPW 4                      // 16-px tiles per wave
__global__ __launch_bounds__(256) void k_qkv(const void* __restrict x,
        const float* __restrict wf, const int* __restrict flag,
        bf16* __restrict qws, bf16* __restrict ekws, bf16* __restrict vws) {
    const int lane = threadIdx.x & 63;
    const int m = lane & 15, g = lane >> 4;       // frag col / lane-group
    const int wave = blockIdx.x * 4 + (threadIdx.x >> 6);
    const int px0 = wave * (TPW * 16);            // 64 px per wave, batch-aligned
    const int b = px0 >> 16;
    const int n0 = px0 & 0xFFFF;
    const int isf = *flag;                        // wave-uniform

    // --- A-fragments: lane holds W[mt*16+m][kh*32 + g*8 + i], i=0..7 ---
    short8 a[7][2];
    #pragma unroll
    for (int mt = 0; mt < 7; ++mt)
        #pragma unroll
        for (int kh = 0; kh < 2; ++kh) {
            const float* wr = wf + WALL_OFF + (mt * 16 + m) * 64 + kh * 32 + g * 8;
            short8 t;
            #pragma unroll
            for (int i = 0; i < 8; ++i) t[i] = f2bf_s(wr[i]);
            a[mt][kh] = t;
        }

    // --- bias as MFMA C-init: C[row=oc][col=px], row = g*4 + r ---
    f32x4 bias[7];
    #pragma unroll
    for (int mt = 0; mt < 4; ++mt)
        #pragma unroll
        for (int r = 0; r < 4; ++r) bias[mt][r] = wf[BQ_OFF + mt * 16 + g * 4 + r];
    #pragma unroll
    for (int r = 0; r < 4; ++r) bias[4][r] = 0.0f;        // k has no bias
    #pragma unroll
    for (int mt = 5; mt < 7; ++mt)
        #pragma unroll
        for (int r = 0; r < 4; ++r) bias[mt][r] = wf[BV_OFF + (mt - 5) * 16 + g * 4 + r];

    for (int it = 0; it < TPW; ++it) {
        const int n = n0 + it * 16 + m;
        const size_t p = (size_t)px0 + it * 16 + m;

        // --- B-fragments direct from global: lane reads c = kh*32+g*8+i at
        //     pixel n; per (i,kh) each 16-lane group covers a 64B (fp32) run.
        short8 bf0, bf1;
        if (isf) {
            const float* xp = (const float*)x + (size_t)b * CIN * NN
                            + (size_t)g * 8 * NN + n;
            #pragma unroll
            for (int i = 0; i < 8; ++i) bf0[i] = f2bf_s(xp[(size_t)i * NN]);
            #pragma unroll
            for (int i = 0; i < 8; ++i) bf1[i] = f2bf_s(xp[(size_t)(32 + i) * NN]);
        } else {
            const unsigned short* xp = (const unsigned short*)x + (size_t)b * CIN * NN
                                     + (size_t)g * 8 * NN + n;
            #pragma unroll
            for (int i = 0; i < 8; ++i) bf0[i] = (short)xp[(size_t)i * NN];
            #pragma unroll
            for (int i = 0; i < 8; ++i) bf1[i] = (short)xp[(size_t)(32 + i) * NN];
        }

        __builtin_amdgcn_sched_barrier(0);        // all cvts issued before MFMA
        asm volatile("s_nop 3");                  // VALU->MFMA srcA/B hazard guard
        f32x4 acc[7];
        #pragma unroll
        for (int mt = 0; mt < 7; ++mt) {
            acc[mt] = mfma_init(a[mt][0], bf0, bias[mt]);
            mfma_acc(a[mt][1], bf1, acc[mt]);
        }
        __builtin_amdgcn_sched_barrier(0);        // no epilogue hoisting into MFMAs
        asm volatile("s_nop 7\n\ts_nop 7");       // MFMA->VALU hazard guard

        // --- epilogue: D row = oc = mt*16 + g*4 + r, col = px (lane m) ---
        bf16* qp = qws + (size_t)g * 4 * NP + p;
        #pragma unroll
        for (int mt = 0; mt < 4; ++mt)
            #pragma unroll
            for (int r = 0; r < 4; ++r)
                qp[(size_t)(mt * 16 + r) * NP] = (bf16)acc[mt][r];
        bf16* ep = ekws + (size_t)g * 4 * NP + p;
        #pragma unroll
        for (int r = 0; r < 4; ++r)
            ep[(size_t)r * NP] = (bf16)__expf(acc[4][r]);   // softmax numerator
        bf16* vp = vws + (size_t)g * 4 * NP + p;
        #pragma unroll
        for (int mt = 0; mt < 2; ++mt)
            #pragma unroll
            for (int r = 0; r < 4; ++r)
                vp[(size_t)(mt * 16 + r) * NP] = (bf16)acc[5 + mt][r];
    }
}

// ---------------- K2: lam_c numerators M[k][v] and denominators S[k] -------
#define CHUNKS 64
#define CHPIX  (NN / CHUNKS)      // 1024
#define TILE   256
__global__ __launch_bounds__(512) void k_lamc(const bf16* __restrict ekws,
        const bf16* __restrict vws, float* __restrict Sg, float* __restrict Mg) {
    __shared__ float ek[KC * 257];
    __shared__ float vv[VC * 257];
    int b = blockIdx.y, chunk = blockIdx.x, t = threadIdx.x;
    int kk = t >> 5, vi = t & 31;                 // this thread owns pair (kk, vi)
    size_t base = (size_t)b * NN + (size_t)chunk * CHPIX;
    float acc = 0.0f, sacc = 0.0f;
    for (int tile = 0; tile < CHPIX / TILE; ++tile) {
        size_t tb = base + (size_t)tile * TILE;
        for (int i = t; i < KC * TILE; i += 512) {
            int r = i >> 8, c = i & 255;
            ek[r * 257 + c] = (float)ekws[(size_t)r * NP + tb + c];
        }
        for (int i = t; i < VC * TILE; i += 512) {
            int r = i >> 8, c = i & 255;
            vv[r * 257 + c] = (float)vws[(size_t)r * NP + tb + c];
        }
        __syncthreads();
        for (int i = 0; i < TILE; ++i)
            acc += ek[kk * 257 + i] * vv[vi * 257 + i];
        if (t < KC)
            for (int i = 0; i < TILE; ++i) sacc += ek[t * 257 + i];
        __syncthreads();
    }
    atomicAdd(&Mg[(b * KC + kk) * VC + vi], acc);
    if (t < KC) atomicAdd(&Sg[b * KC + t], sacc);
}

// ---------------- K3: output = q·(lam_c+bp) + (q·Wp) * v-neighborhood -----
__global__ __launch_bounds__(256) void k_out(const bf16* __restrict qws,
        const bf16* __restrict vws, const float* __restrict wf,
        const float* __restrict Sg, const float* __restrict Mg,
        const int* __restrict flag, void* __restrict outv) {
    int y = blockIdx.x, b = blockIdx.y, xc = threadIdx.x;
    int isf = *flag;
    __shared__ float A[KC * VC];                  // lam_c[k][v] + bp[k]
    for (int i = threadIdx.x; i < KC * VC; i += 256) {
        int k = i >> 5;
        A[i] = Mg[b * KC * VC + i] / Sg[b * KC + k] + wf[BP_OFF + k];
    }
    __syncthreads();
    size_t pix = (size_t)b * NN + (size_t)y * WW + xc;

    float q[64];
    #pragma unroll
    for (int o = 0; o < 64; ++o) q[o] = (float)qws[(size_t)o * NP + pix];

    // g[h][t] = q[h,:] · Wp[:,t]  (per-pixel 3x3 filters, one per head)
    float g[HEADS][9];
    #pragma unroll
    for (int h = 0; h < HEADS; ++h)
        #pragma unroll
        for (int tn = 0; tn < 9; ++tn) {
            float acc = 0.0f;
            #pragma unroll
            for (int k = 0; k < 16; ++k) acc += q[h * 16 + k] * wf[WP_OFF + k * 9 + tn];
            g[h][tn] = acc;
        }

    for (int v = 0; v < VC; ++v) {
        float Ac[16];
        #pragma unroll
        for (int k = 0; k < 16; ++k) Ac[k] = A[k * VC + v];
        float vn[9];
        const bf16* vp = vws + (size_t)v * NP + (size_t)b * NN;
        #pragma unroll
        for (int dy = -1; dy <= 1; ++dy)
            #pragma unroll
            for (int dx = -1; dx <= 1; ++dx) {
                int yy = y + dy, xx = xc + dx;
                bool ok = (yy >= 0) & (yy < HH) & (xx >= 0) & (xx < WW);
                vn[(dy + 1) * 3 + dx + 1] = ok ? (float)vp[yy * WW + xx] : 0.0f;
            }
        #pragma unroll
        for (int h = 0; h < HEADS; ++h) {
            float acc = 0.0f;
            #pragma unroll
            for (int k = 0; k < 16; ++k) acc += q[h * 16 + k] * Ac[k];
            #pragma unroll
            for (int tn = 0; tn < 9; ++tn) acc += g[h][tn] * vn[tn];
            size_t idx = ((size_t)(b * HEADS + h) * VC + v) * NN + (size_t)y * WW + xc;
            if (isf) ((float*)outv)[idx] = acc;
            else     ((bf16*)outv)[idx] = (bf16)acc;
        }
    }
}

extern "C" void kernel_launch(void* const* d_in, const int* in_sizes, int n_in,
                              void* d_out, int out_size, void* d_ws, size_t ws_size,
                              hipStream_t stream) {
    float* wf = (float*)d_ws;
    int* flag = (int*)wf + FLAG_OFF;
    bf16* qws  = (bf16*)((char*)d_ws + BF_BASE);
    bf16* ekws = qws + (size_t)QC * NP;
    bf16* vws  = ekws + (size_t)KC * NP;
    // ws usage: 65536 + (64+16+32)*524288*2 bytes ≈ 117.5 MB

    k_detect<<<1, 64, 0, stream>>>((const unsigned short*)d_in[0], flag);
    k_prep<<<1, 256, 0, stream>>>(d_in[1], d_in[2], d_in[3], d_in[4], d_in[5],
                                  d_in[6], d_in[7], d_in[8], d_in[9], wf, flag);
    k_qkv<<<NP / 256, 256, 0, stream>>>(d_in[0], wf, flag, qws, ekws, vws);
    k_lamc<<<dim3(CHUNKS, BB), 512, 0, stream>>>(ekws, vws, wf + S_OFF, wf + M_OFF);
    k_out<<<dim3(HH, BB), 256, 0, stream>>>(qws, vws, wf, wf + S_OFF, wf + M_OFF,
                                            flag, d_out);
}

// Round 2
// 599.888 us; speedup vs baseline: 1.7093x; 1.1751x over previous
//
#include <hip/hip_runtime.h>
#include <hip/hip_bf16.h>
#include <cstddef>

// Problem constants
#define BB    8
#define CIN   64
#define HH    256
#define WW    256
#define NN    65536            // H*W per batch
#define NP    (BB*NN)          // total pixels = 524288
#define QC    64               // q channels = HEADS*QD
#define KC    16               // k channels = QD*U
#define VC    32               // v channels = VD*U
#define HEADS 4
#define QD    16

// fp32 scratch (float-element offsets within ws)
#define WALL_OFF 0             // 112x64 BN-folded [Wq(0-63); Wk(64-79); Wv(80-111)]
#define BQ_OFF 7168            // 64
#define BV_OFF 7232            // 32
#define WP_OFF 7264            // 16*9
#define BP_OFF 7408            // 16
#define S_OFF  7424            // B*KC softmax denominators
#define M_OFF  7552            // B*KC*VC numerators
#define SMALL_END 11648
#define FLAG_OFF 12000         // int flag: 1 = inputs are fp32, 0 = bf16
#define BF_BASE 65536          // byte offset where bf16 staging starts

typedef __hip_bfloat16 bf16;
typedef __attribute__((ext_vector_type(8))) short short8;   // 8 bf16 (4 VGPRs)
typedef __attribute__((ext_vector_type(4))) short short4v;  // 4 bf16 (8B store)
typedef __attribute__((ext_vector_type(4))) float f32x4;    // MFMA C/D

#define MFMA16(a, b, c) __builtin_amdgcn_mfma_f32_16x16x32_bf16((a), (b), (c), 0, 0, 0)

__device__ __forceinline__ short f2bf_s(float f) {
    bf16 h = (bf16)f;
    return __builtin_bit_cast(short, h);
}
__device__ __forceinline__ float bf2f(short u) {
    unsigned x = ((unsigned)(unsigned short)u) << 16;
    return __builtin_bit_cast(float, x);
}

// ---------------- K-1: detect input dtype --------------------------------
__global__ void k_detect(const unsigned short* __restrict xu, int* __restrict flag) {
    if (threadIdx.x == 0 && blockIdx.x == 0) {
        int big = 0, zero = 0;
        for (int i = 0; i < 256; ++i) {
            unsigned short u = xu[i];
            int e = (u >> 7) & 0xFF;
            big  += (e >= 134);
            zero += (u == 0);
        }
        *flag = (big > 4 || zero > 64) ? 1 : 0;
    }
}

__device__ __forceinline__ float ldin(const void* p, int i, int isf) {
    return isf ? ((const float*)p)[i] : (float)(((const bf16*)p)[i]);
}

// ---------------- K0: weight prep (convert to fp32, fold BN) + zero S/M ----
__global__ void k_prep(const void* __restrict wq, const void* __restrict gq,
                       const void* __restrict bq, const void* __restrict wk,
                       const void* __restrict wv, const void* __restrict gv,
                       const void* __restrict bv, const void* __restrict wp,
                       const void* __restrict bp, float* __restrict wf,
                       const int* __restrict flag) {
    int t = threadIdx.x;
    int isf = *flag;
    float rs = rsqrtf(1.0f + 1e-5f);
    for (int i = t; i < 4096; i += 256)
        wf[WALL_OFF + i] = ldin(wq, i, isf) * (ldin(gq, i>>6, isf) * rs);
    for (int i = t; i < 1024; i += 256)
        wf[WALL_OFF + 4096 + i] = ldin(wk, i, isf);
    for (int i = t; i < 2048; i += 256)
        wf[WALL_OFF + 5120 + i] = ldin(wv, i, isf) * (ldin(gv, i>>6, isf) * rs);
    for (int i = t; i < 64;   i += 256) wf[BQ_OFF+i] = ldin(bq, i, isf);
    for (int i = t; i < 32;   i += 256) wf[BV_OFF+i] = ldin(bv, i, isf);
    for (int i = t; i < 144;  i += 256) wf[WP_OFF+i] = ldin(wp, i, isf);
    for (int i = t; i < 16;   i += 256) wf[BP_OFF+i] = ldin(bp, i, isf);
    for (int i = t; i < SMALL_END - S_OFF; i += 256) wf[S_OFF + i] = 0.0f;  // zero S,M
}

// ---------------- K1: q / exp(k) / v via MFMA ------------------------------
// GEMM: out[112][p] = W[112][64] * x[64][p]. A (weights) preloaded in VGPRs;
// B (x) loaded straight from global in fragment order. Builtin MFMA so the
// compiler pipelines loads across tile-iters (no sched_barrier walls).
// q stored [pix][64ch] (packed 8B runs); ek/v stored [ch][pix].
#define TPW 4                      // 16-px tiles per wave
__global__ __launch_bounds__(256) void k_qkv(const void* __restrict x,
        const float* __restrict wf, const int* __restrict flag,
        bf16* __restrict qws2, bf16* __restrict ekws, bf16* __restrict vws) {
    const int lane = threadIdx.x & 63;
    const int m = lane & 15, g = lane >> 4;       // frag col / lane-group
    const int wave = blockIdx.x * 4 + (threadIdx.x >> 6);
    const int px0 = wave * (TPW * 16);            // 64 px per wave, batch-aligned
    const int b = px0 >> 16;
    const int n0 = px0 & 0xFFFF;
    const int isf = *flag;                        // wave-uniform

    // --- A-fragments: lane holds W[mt*16+m][kh*32 + g*8 + i], i=0..7 ---
    short8 a[7][2];
    #pragma unroll
    for (int mt = 0; mt < 7; ++mt)
        #pragma unroll
        for (int kh = 0; kh < 2; ++kh) {
            const float* wr = wf + WALL_OFF + (mt * 16 + m) * 64 + kh * 32 + g * 8;
            short8 t;
            #pragma unroll
            for (int i = 0; i < 8; ++i) t[i] = f2bf_s(wr[i]);
            a[mt][kh] = t;
        }

    // --- bias as MFMA C-init: C[row=oc][col=px], row = g*4 + r ---
    f32x4 bias[7];
    #pragma unroll
    for (int mt = 0; mt < 4; ++mt)
        #pragma unroll
        for (int r = 0; r < 4; ++r) bias[mt][r] = wf[BQ_OFF + mt * 16 + g * 4 + r];
    #pragma unroll
    for (int r = 0; r < 4; ++r) bias[4][r] = 0.0f;        // k has no bias
    #pragma unroll
    for (int mt = 5; mt < 7; ++mt)
        #pragma unroll
        for (int r = 0; r < 4; ++r) bias[mt][r] = wf[BV_OFF + (mt - 5) * 16 + g * 4 + r];

    #pragma unroll
    for (int it = 0; it < TPW; ++it) {
        const int n = n0 + it * 16 + m;
        const size_t p = (size_t)px0 + it * 16 + m;

        // --- B-fragments direct from global: lane reads c = kh*32+g*8+i at
        //     pixel n; per (i,kh) each 16-lane group covers a contiguous run.
        short8 bf0, bf1;
        if (isf) {
            const float* xp = (const float*)x + (size_t)b * CIN * NN
                            + (size_t)g * 8 * NN + n;
            #pragma unroll
            for (int i = 0; i < 8; ++i) bf0[i] = f2bf_s(xp[(size_t)i * NN]);
            #pragma unroll
            for (int i = 0; i < 8; ++i) bf1[i] = f2bf_s(xp[(size_t)(32 + i) * NN]);
        } else {
            const unsigned short* xp = (const unsigned short*)x + (size_t)b * CIN * NN
                                     + (size_t)g * 8 * NN + n;
            #pragma unroll
            for (int i = 0; i < 8; ++i) bf0[i] = (short)xp[(size_t)i * NN];
            #pragma unroll
            for (int i = 0; i < 8; ++i) bf1[i] = (short)xp[(size_t)(32 + i) * NN];
        }

        f32x4 acc[7];
        #pragma unroll
        for (int mt = 0; mt < 7; ++mt) {
            acc[mt] = MFMA16(a[mt][0], bf0, bias[mt]);
            acc[mt] = MFMA16(a[mt][1], bf1, acc[mt]);
        }

        // --- epilogue: D row = oc = mt*16 + g*4 + r, col = px (lane m) ---
        // q -> [pix][64]: 4 packed 8B stores
        bf16* qp = qws2 + p * 64;
        #pragma unroll
        for (int mt = 0; mt < 4; ++mt) {
            short4v pk;
            #pragma unroll
            for (int r = 0; r < 4; ++r) pk[r] = f2bf_s(acc[mt][r]);
            *(short4v*)(qp + mt * 16 + g * 4) = pk;
        }
        // ek -> [ch][pix]
        #pragma unroll
        for (int r = 0; r < 4; ++r)
            ekws[(size_t)(g * 4 + r) * NP + p] = (bf16)__expf(acc[4][r]);
        // v -> [ch][pix]
        #pragma unroll
        for (int mt = 0; mt < 2; ++mt)
            #pragma unroll
            for (int r = 0; r < 4; ++r)
                vws[(size_t)(mt * 16 + g * 4 + r) * NP + p] = (bf16)acc[5 + mt][r];
    }
}

// ---------------- K2: lam_c via MFMA over pixels ---------------------------
// M[16k][32v] = sum_px ek[k][px]*v[v][px]; S[k] = sum_px ek[k][px].
// A-frag = ek (16 rows x 32px K-step), B-frags = v tiles; both contiguous
// dwordx4 loads in the [ch][pix] layout. Block-level LDS reduce, then atomics.
__global__ __launch_bounds__(256) void k_lamc(const bf16* __restrict ekws,
        const bf16* __restrict vws, float* __restrict Sg, float* __restrict Mg) {
    __shared__ float MM[4][512];
    __shared__ float SS[4][16];
    const int b = blockIdx.y, chunk = blockIdx.x;
    const int t = threadIdx.x, w = t >> 6, lane = t & 63;
    const int m = lane & 15, g = lane >> 4;
    const size_t px0 = (size_t)b * NN + (size_t)chunk * 1024 + (size_t)w * 256;

    f32x4 acc0 = {0.f, 0.f, 0.f, 0.f}, acc1 = {0.f, 0.f, 0.f, 0.f};
    float s = 0.0f;
    #pragma unroll
    for (int st = 0; st < 8; ++st) {
        const size_t p = px0 + st * 32 + g * 8;
        short8 afr = *(const short8*)(ekws + (size_t)m * NP + p);
        short8 b0  = *(const short8*)(vws + (size_t)m * NP + p);
        short8 b1  = *(const short8*)(vws + (size_t)(16 + m) * NP + p);
        acc0 = MFMA16(afr, b0, acc0);
        acc1 = MFMA16(afr, b1, acc1);
        #pragma unroll
        for (int i = 0; i < 8; ++i) s += bf2f(afr[i]);
    }
    // S: reduce the 4 g-lanes of each row m
    s += __shfl_xor(s, 16);
    s += __shfl_xor(s, 32);
    if (g == 0) SS[w][m] = s;
    // M: lane holds D[k=g*4+r][v=tile*16+m]
    #pragma unroll
    for (int r = 0; r < 4; ++r) {
        MM[w][(g * 4 + r) * 32 + m]      = acc0[r];
        MM[w][(g * 4 + r) * 32 + 16 + m] = acc1[r];
    }
    __syncthreads();
    for (int i = t; i < 512; i += 256) {
        float v4 = MM[0][i] + MM[1][i] + MM[2][i] + MM[3][i];
        atomicAdd(&Mg[b * 512 + i], v4);
    }
    if (t < 16) atomicAdd(&Sg[b * 16 + t], SS[0][t] + SS[1][t] + SS[2][t] + SS[3][t]);
}

// ---------------- K3: output = q·(lam_c+bp) + (q·Wp) * v-neighborhood -----
// Block = one image row. q loaded as 8 dwordx4 ([pix][64] layout); v 3-row
// window LDS-staged per 16-ch half (halo + OOB zeros in LDS). No spills.
__global__ __launch_bounds__(256) void k_out(const bf16* __restrict qws2,
        const bf16* __restrict vws, const float* __restrict wf,
        const float* __restrict Sg, const float* __restrict Mg,
        const int* __restrict flag, void* __restrict outv) {
    const int y = blockIdx.x, b = blockIdx.y, xc = threadIdx.x;
    const int isf = *flag;
    __shared__ float As[512];                 // [v][k] : lam_c + bp, transposed
    __shared__ float WPs[144];                // Wp[k][9]
    __shared__ unsigned short VS[16 * 3 * 272];  // [ch][3 rows][272] bf16, data @8

    for (int i = threadIdx.x; i < 512; i += 256) {
        int k = i & 15, v = i >> 4;
        As[i] = Mg[b * 512 + k * 32 + v] / Sg[b * 16 + k] + wf[BP_OFF + k];
    }
    if (threadIdx.x < 144) WPs[threadIdx.x] = wf[WP_OFF + threadIdx.x];
    __syncthreads();

    const size_t pix = (size_t)b * NN + (size_t)y * WW + xc;
    const short8* qrow = (const short8*)(qws2 + pix * 64);
    float qf[64];
    #pragma unroll
    for (int j = 0; j < 8; ++j) {
        short8 qv = qrow[j];
        #pragma unroll
        for (int e = 0; e < 8; ++e) qf[j * 8 + e] = bf2f(qv[e]);
    }

    // g[h][t] = q[h,:] · Wp[:,t]
    float g4[HEADS][9];
    #pragma unroll
    for (int h = 0; h < HEADS; ++h)
        #pragma unroll
        for (int tn = 0; tn < 9; ++tn) g4[h][tn] = 0.0f;
    #pragma unroll
    for (int k = 0; k < 16; ++k)
        #pragma unroll
        for (int tn = 0; tn < 9; ++tn) {
            float w = WPs[k * 9 + tn];
            #pragma unroll
            for (int h = 0; h < HEADS; ++h) g4[h][tn] += qf[h * 16 + k] * w;
        }

    for (int half = 0; half < 2; ++half) {
        // --- stage 16 ch x 3 rows of v into LDS (vectorized) ---
        #pragma unroll
        for (int kk = 0; kk < 6; ++kk) {
            int idx = threadIdx.x + kk * 256;          // 1536 16B-chunks
            int pair = idx >> 5, off = (idx & 31) * 8; // pair=(j,c), off=px start
            int c = pair & 15, j = pair >> 4;
            int yy = y + j - 1;
            short8 val = {0, 0, 0, 0, 0, 0, 0, 0};
            if (yy >= 0 && yy < HH)
                val = *(const short8*)(vws + (size_t)(half * 16 + c) * NP
                                       + (size_t)b * NN + (size_t)yy * WW + off);
            *(short8*)&VS[c * 816 + j * 272 + 8 + off] = val;
        }
        if (threadIdx.x < 96) {                        // x-halo zeros
            int pr = threadIdx.x >> 1, side = threadIdx.x & 1;
            int c = pr & 15, j = pr >> 4;
            VS[c * 816 + j * 272 + (side ? 264 : 7)] = 0;
        }
        __syncthreads();

        #pragma unroll 2
        for (int vl = 0; vl < 16; ++vl) {
            const int vc = half * 16 + vl;
            float vnf[9];
            const unsigned short* vb = &VS[vl * 816 + 8 + xc - 1];
            #pragma unroll
            for (int j = 0; j < 3; ++j)
                #pragma unroll
                for (int dx = 0; dx < 3; ++dx)
                    vnf[j * 3 + dx] = bf2f((short)vb[j * 272 + dx]);
            float Ak[16];
            const f32x4* ap = (const f32x4*)&As[vc * 16];
            #pragma unroll
            for (int qq = 0; qq < 4; ++qq) {
                f32x4 a4 = ap[qq];
                #pragma unroll
                for (int e = 0; e < 4; ++e) Ak[qq * 4 + e] = a4[e];
            }
            #pragma unroll
            for (int h = 0; h < HEADS; ++h) {
                float acc = 0.0f;
                #pragma unroll
                for (int k = 0; k < 16; ++k) acc += qf[h * 16 + k] * Ak[k];
                #pragma unroll
                for (int tn = 0; tn < 9; ++tn) acc += g4[h][tn] * vnf[tn];
                size_t idx2 = ((size_t)(b * HEADS + h) * VC + vc) * NN
                            + (size_t)y * WW + xc;
                if (isf) ((float*)outv)[idx2] = acc;
                else     ((bf16*)outv)[idx2] = (bf16)acc;
            }
        }
        __syncthreads();
    }
}

extern "C" void kernel_launch(void* const* d_in, const int* in_sizes, int n_in,
                              void* d_out, int out_size, void* d_ws, size_t ws_size,
                              hipStream_t stream) {
    float* wf = (float*)d_ws;
    int* flag = (int*)wf + FLAG_OFF;
    bf16* qws2 = (bf16*)((char*)d_ws + BF_BASE);
    bf16* ekws = qws2 + (size_t)QC * NP;
    bf16* vws  = ekws + (size_t)KC * NP;
    // ws usage: 65536 + (64+16+32)*524288*2 bytes ≈ 117.5 MB

    k_detect<<<1, 64, 0, stream>>>((const unsigned short*)d_in[0], flag);
    k_prep<<<1, 256, 0, stream>>>(d_in[1], d_in[2], d_in[3], d_in[4], d_in[5],
                                  d_in[6], d_in[7], d_in[8], d_in[9], wf, flag);
    k_qkv<<<NP / 256, 256, 0, stream>>>(d_in[0], wf, flag, qws2, ekws, vws);
    k_lamc<<<dim3(64, BB), 256, 0, stream>>>(ekws, vws, wf + S_OFF, wf + M_OFF);
    k_out<<<dim3(HH, BB), 256, 0, stream>>>(qws2, vws, wf, wf + S_OFF, wf + M_OFF,
                                            flag, d_out);
}

// Round 3
// 529.738 us; speedup vs baseline: 1.9356x; 1.1324x over previous
//
#include <hip/hip_runtime.h>
#include <hip/hip_bf16.h>
#include <cstddef>

// Problem constants
#define BB    8
#define CIN   64
#define HH    256
#define WW    256
#define NN    65536            // H*W per batch
#define NP    (BB*NN)          // total pixels = 524288
#define QC    64               // q channels = HEADS*QD
#define KC    16               // k channels = QD*U
#define VC    32               // v channels = VD*U
#define HEADS 4
#define QD    16

// fp32 scratch (float-element offsets within ws)
#define WALL_OFF 0             // 112x64 BN-folded [Wq(0-63); Wk(64-79); Wv(80-111)]
#define BQ_OFF 7168            // 64
#define BV_OFF 7232            // 32
#define WP_OFF 7264            // 16*9
#define BP_OFF 7408            // 16
#define S_OFF  7424            // B*KC softmax denominators
#define M_OFF  7552            // B*KC*VC numerators
#define SMALL_END 11648
#define FLAG_OFF 12000         // int flag: 1 = inputs are fp32, 0 = bf16
#define BF_BASE 65536          // byte offset where bf16 staging starts

typedef __hip_bfloat16 bf16;
typedef __attribute__((ext_vector_type(8))) short short8;   // 8 bf16 (4 VGPRs)
typedef __attribute__((ext_vector_type(4))) short short4v;  // 4 bf16 (8B store)
typedef __attribute__((ext_vector_type(4))) float f32x4;    // MFMA C/D

#define MFMA16(a, b, c) __builtin_amdgcn_mfma_f32_16x16x32_bf16((a), (b), (c), 0, 0, 0)

__device__ __forceinline__ short f2bf_s(float f) {
    bf16 h = (bf16)f;
    return __builtin_bit_cast(short, h);
}
__device__ __forceinline__ float bf2f(short u) {
    unsigned x = ((unsigned)(unsigned short)u) << 16;
    return __builtin_bit_cast(float, x);
}

// ---------------- K-1: detect input dtype --------------------------------
__global__ void k_detect(const unsigned short* __restrict xu, int* __restrict flag) {
    if (threadIdx.x == 0 && blockIdx.x == 0) {
        int big = 0, zero = 0;
        for (int i = 0; i < 256; ++i) {
            unsigned short u = xu[i];
            int e = (u >> 7) & 0xFF;
            big  += (e >= 134);
            zero += (u == 0);
        }
        *flag = (big > 4 || zero > 64) ? 1 : 0;
    }
}

__device__ __forceinline__ float ldin(const void* p, int i, int isf) {
    return isf ? ((const float*)p)[i] : (float)(((const bf16*)p)[i]);
}

// ---------------- K0: weight prep (convert to fp32, fold BN) + zero S/M ----
__global__ void k_prep(const void* __restrict wq, const void* __restrict gq,
                       const void* __restrict bq, const void* __restrict wk,
                       const void* __restrict wv, const void* __restrict gv,
                       const void* __restrict bv, const void* __restrict wp,
                       const void* __restrict bp, float* __restrict wf,
                       const int* __restrict flag) {
    int t = threadIdx.x;
    int isf = *flag;
    float rs = rsqrtf(1.0f + 1e-5f);
    for (int i = t; i < 4096; i += 256)
        wf[WALL_OFF + i] = ldin(wq, i, isf) * (ldin(gq, i>>6, isf) * rs);
    for (int i = t; i < 1024; i += 256)
        wf[WALL_OFF + 4096 + i] = ldin(wk, i, isf);
    for (int i = t; i < 2048; i += 256)
        wf[WALL_OFF + 5120 + i] = ldin(wv, i, isf) * (ldin(gv, i>>6, isf) * rs);
    for (int i = t; i < 64;   i += 256) wf[BQ_OFF+i] = ldin(bq, i, isf);
    for (int i = t; i < 32;   i += 256) wf[BV_OFF+i] = ldin(bv, i, isf);
    for (int i = t; i < 144;  i += 256) wf[WP_OFF+i] = ldin(wp, i, isf);
    for (int i = t; i < 16;   i += 256) wf[BP_OFF+i] = ldin(bp, i, isf);
    for (int i = t; i < SMALL_END - S_OFF; i += 256) wf[S_OFF + i] = 0.0f;  // zero S,M
}

// ---------------- K1: q / exp(k) / v via MFMA ------------------------------
// GEMM: out[112][p] = W[112][64] * x[64][p]. A (weights) preloaded in VGPRs;
// B (x) loaded straight from global in fragment order. TPW=2 so the grid is
// 16384 waves (full oversubscription) to hide the strided-load latency.
// q stored [pix][64ch] (packed 8B runs); ek/v stored [ch][pix].
#define TPW 2                      // 16-px tiles per wave
__global__ __launch_bounds__(256) void k_qkv(const void* __restrict x,
        const float* __restrict wf, const int* __restrict flag,
        bf16* __restrict qws2, bf16* __restrict ekws, bf16* __restrict vws) {
    const int lane = threadIdx.x & 63;
    const int m = lane & 15, g = lane >> 4;       // frag col / lane-group
    const int wave = blockIdx.x * 4 + (threadIdx.x >> 6);
    const int px0 = wave * (TPW * 16);            // 32 px per wave, batch-aligned
    const int b = px0 >> 16;
    const int n0 = px0 & 0xFFFF;
    const int isf = *flag;                        // wave-uniform

    // --- A-fragments: lane holds W[mt*16+m][kh*32 + g*8 + i], i=0..7 ---
    short8 a[7][2];
    #pragma unroll
    for (int mt = 0; mt < 7; ++mt)
        #pragma unroll
        for (int kh = 0; kh < 2; ++kh) {
            const float* wr = wf + WALL_OFF + (mt * 16 + m) * 64 + kh * 32 + g * 8;
            short8 t;
            #pragma unroll
            for (int i = 0; i < 8; ++i) t[i] = f2bf_s(wr[i]);
            a[mt][kh] = t;
        }

    // --- bias as MFMA C-init: C[row=oc][col=px], row = g*4 + r ---
    f32x4 bias[7];
    #pragma unroll
    for (int mt = 0; mt < 4; ++mt)
        #pragma unroll
        for (int r = 0; r < 4; ++r) bias[mt][r] = wf[BQ_OFF + mt * 16 + g * 4 + r];
    #pragma unroll
    for (int r = 0; r < 4; ++r) bias[4][r] = 0.0f;        // k has no bias
    #pragma unroll
    for (int mt = 5; mt < 7; ++mt)
        #pragma unroll
        for (int r = 0; r < 4; ++r) bias[mt][r] = wf[BV_OFF + (mt - 5) * 16 + g * 4 + r];

    #pragma unroll
    for (int it = 0; it < TPW; ++it) {
        const int n = n0 + it * 16 + m;
        const size_t p = (size_t)px0 + it * 16 + m;

        // --- B-fragments direct from global: lane reads c = kh*32+g*8+i at
        //     pixel n; per (i,kh) each 16-lane group covers a contiguous run.
        short8 bf0, bf1;
        if (isf) {
            const float* xp = (const float*)x + (size_t)b * CIN * NN
                            + (size_t)g * 8 * NN + n;
            #pragma unroll
            for (int i = 0; i < 8; ++i) bf0[i] = f2bf_s(xp[(size_t)i * NN]);
            #pragma unroll
            for (int i = 0; i < 8; ++i) bf1[i] = f2bf_s(xp[(size_t)(32 + i) * NN]);
        } else {
            const unsigned short* xp = (const unsigned short*)x + (size_t)b * CIN * NN
                                     + (size_t)g * 8 * NN + n;
            #pragma unroll
            for (int i = 0; i < 8; ++i) bf0[i] = (short)xp[(size_t)i * NN];
            #pragma unroll
            for (int i = 0; i < 8; ++i) bf1[i] = (short)xp[(size_t)(32 + i) * NN];
        }

        f32x4 acc[7];
        #pragma unroll
        for (int mt = 0; mt < 7; ++mt) {
            acc[mt] = MFMA16(a[mt][0], bf0, bias[mt]);
            acc[mt] = MFMA16(a[mt][1], bf1, acc[mt]);
        }

        // --- epilogue: D row = oc = mt*16 + g*4 + r, col = px (lane m) ---
        // q -> [pix][64]: 4 packed 8B stores
        bf16* qp = qws2 + p * 64;
        #pragma unroll
        for (int mt = 0; mt < 4; ++mt) {
            short4v pk;
            #pragma unroll
            for (int r = 0; r < 4; ++r) pk[r] = f2bf_s(acc[mt][r]);
            *(short4v*)(qp + mt * 16 + g * 4) = pk;
        }
        // ek -> [ch][pix]
        #pragma unroll
        for (int r = 0; r < 4; ++r)
            ekws[(size_t)(g * 4 + r) * NP + p] = (bf16)__expf(acc[4][r]);
        // v -> [ch][pix]
        #pragma unroll
        for (int mt = 0; mt < 2; ++mt)
            #pragma unroll
            for (int r = 0; r < 4; ++r)
                vws[(size_t)(mt * 16 + g * 4 + r) * NP + p] = (bf16)acc[5 + mt][r];
    }
}

// ---------------- K2: lam_c via MFMA over pixels ---------------------------
// M[16k][32v] = sum_px ek[k][px]*v[v][px]; S[k] = sum_px ek[k][px].
// Chunk = 256 px (grid 2048 blocks -> 32 waves/CU) so load latency is hidden
// by TLP instead of being exposed at 2 waves/SIMD.
#define LCHUNK 256
__global__ __launch_bounds__(256) void k_lamc(const bf16* __restrict ekws,
        const bf16* __restrict vws, float* __restrict Sg, float* __restrict Mg) {
    __shared__ float MM[4][512];
    __shared__ float SS[4][16];
    const int b = blockIdx.y, chunk = blockIdx.x;
    const int t = threadIdx.x, w = t >> 6, lane = t & 63;
    const int m = lane & 15, g = lane >> 4;
    const size_t px0 = (size_t)b * NN + (size_t)chunk * LCHUNK + (size_t)w * 64;

    f32x4 acc0 = {0.f, 0.f, 0.f, 0.f}, acc1 = {0.f, 0.f, 0.f, 0.f};
    float s = 0.0f;
    #pragma unroll
    for (int st = 0; st < 2; ++st) {
        const size_t p = px0 + st * 32 + g * 8;
        short8 afr = *(const short8*)(ekws + (size_t)m * NP + p);
        short8 b0  = *(const short8*)(vws + (size_t)m * NP + p);
        short8 b1  = *(const short8*)(vws + (size_t)(16 + m) * NP + p);
        acc0 = MFMA16(afr, b0, acc0);
        acc1 = MFMA16(afr, b1, acc1);
        #pragma unroll
        for (int i = 0; i < 8; ++i) s += bf2f(afr[i]);
    }
    // S: reduce the 4 g-lanes of each row m
    s += __shfl_xor(s, 16);
    s += __shfl_xor(s, 32);
    if (g == 0) SS[w][m] = s;
    // M: lane holds D[k=g*4+r][v=tile*16+m]
    #pragma unroll
    for (int r = 0; r < 4; ++r) {
        MM[w][(g * 4 + r) * 32 + m]      = acc0[r];
        MM[w][(g * 4 + r) * 32 + 16 + m] = acc1[r];
    }
    __syncthreads();
    for (int i = t; i < 512; i += 256) {
        float v4 = MM[0][i] + MM[1][i] + MM[2][i] + MM[3][i];
        atomicAdd(&Mg[b * 512 + i], v4);
    }
    if (t < 16) atomicAdd(&Sg[b * 16 + t], SS[0][t] + SS[1][t] + SS[2][t] + SS[3][t]);
}

// ---------------- K3: output = q·(lam_c+bp) + (q·Wp) * v-neighborhood -----
// Thread owns (pixel, head-pair): qf[32] not qf[64] -> ~100 VGPR. Block =
// 128 px x 2 head-groups; all 32 v-channels' 3-row windows staged once in
// LDS (single barrier). Grid = 2 blocks/row x 256 rows x 8 batches = 4096.
__global__ __launch_bounds__(256) void k_out(const bf16* __restrict qws2,
        const bf16* __restrict vws, const float* __restrict wf,
        const float* __restrict Sg, const float* __restrict Mg,
        const int* __restrict flag, void* __restrict outv) {
    const int y = blockIdx.x >> 1, xh = blockIdx.x & 1, b = blockIdx.y;
    const int tid = threadIdx.x;
    const int pxl = tid & 127, hg = tid >> 7;     // local pixel / head-group
    const int px0 = xh * 128;
    const int isf = *flag;

    __shared__ float As[512];                     // [v][k] : lam_c + bp
    __shared__ float WPs[144];                    // Wp[k][9]
    __shared__ unsigned short VS[32 * 3 * 144];   // [ch][3 rows][144] bf16, x0@idx8

    for (int i = tid; i < 512; i += 256) {
        int k = i & 15, v = i >> 4;
        As[i] = Mg[b * 512 + k * 32 + v] / Sg[b * 16 + k] + wf[BP_OFF + k];
    }
    if (tid < 144) WPs[tid] = wf[WP_OFF + tid];

    // --- stage v: 32 ch x 3 rows x 144 px (window px0-8 .. px0+135) ---
    #pragma unroll
    for (int kk = 0; kk < 7; ++kk) {
        int idx = tid + kk * 256;                 // (c,j,i): 32*3*18 = 1728
        if (idx < 1728) {
            int c = idx / 54, rem = idx - c * 54;
            int j = rem / 18, i = rem - j * 18;
            int yy = y + j - 1;
            int x0 = px0 - 8 + i * 8;
            short8 val = {0, 0, 0, 0, 0, 0, 0, 0};
            if (yy >= 0 && yy < HH && x0 >= 0 && x0 <= WW - 8)
                val = *(const short8*)(vws + (size_t)c * NP + (size_t)b * NN
                                       + (size_t)yy * WW + x0);
            *(short8*)&VS[(c * 3 + j) * 144 + i * 8] = val;
        }
    }
    __syncthreads();

    // --- q for this thread's 2 heads (32 channels) ---
    const size_t pix = (size_t)b * NN + (size_t)y * WW + px0 + pxl;
    const short8* qrow = (const short8*)(qws2 + pix * 64) + hg * 4;
    float qf[32];
    #pragma unroll
    for (int j = 0; j < 4; ++j) {
        short8 qv = qrow[j];
        #pragma unroll
        for (int e = 0; e < 8; ++e) qf[j * 8 + e] = bf2f(qv[e]);
    }

    // g4[hl][t] = q[hl,:] . Wp[:,t]
    float g4[2][9];
    #pragma unroll
    for (int hl = 0; hl < 2; ++hl)
        #pragma unroll
        for (int tn = 0; tn < 9; ++tn) g4[hl][tn] = 0.0f;
    #pragma unroll
    for (int k = 0; k < 16; ++k)
        #pragma unroll
        for (int tn = 0; tn < 9; ++tn) {
            float w = WPs[k * 9 + tn];
            g4[0][tn] += qf[k] * w;
            g4[1][tn] += qf[16 + k] * w;
        }

    const size_t obase = ((size_t)(b * HEADS + hg * 2) * VC) * NN
                       + (size_t)y * WW + px0 + pxl;
    #pragma unroll 2
    for (int vc = 0; vc < VC; ++vc) {
        float vnf[9];
        const unsigned short* vb = &VS[vc * 3 * 144 + 7 + pxl];
        #pragma unroll
        for (int j = 0; j < 3; ++j)
            #pragma unroll
            for (int dx = 0; dx < 3; ++dx)
                vnf[j * 3 + dx] = bf2f((short)vb[j * 144 + dx]);
        float Ak[16];
        const f32x4* ap = (const f32x4*)&As[vc * 16];
        #pragma unroll
        for (int qq = 0; qq < 4; ++qq) {
            f32x4 a4 = ap[qq];
            #pragma unroll
            for (int e = 0; e < 4; ++e) Ak[qq * 4 + e] = a4[e];
        }
        #pragma unroll
        for (int hl = 0; hl < 2; ++hl) {
            float acc = 0.0f;
            #pragma unroll
            for (int k = 0; k < 16; ++k) acc += qf[hl * 16 + k] * Ak[k];
            #pragma unroll
            for (int tn = 0; tn < 9; ++tn) acc += g4[hl][tn] * vnf[tn];
            size_t idx2 = obase + ((size_t)hl * VC + vc) * NN;
            if (isf) ((float*)outv)[idx2] = acc;
            else     ((bf16*)outv)[idx2] = (bf16)acc;
        }
    }
}

extern "C" void kernel_launch(void* const* d_in, const int* in_sizes, int n_in,
                              void* d_out, int out_size, void* d_ws, size_t ws_size,
                              hipStream_t stream) {
    float* wf = (float*)d_ws;
    int* flag = (int*)wf + FLAG_OFF;
    bf16* qws2 = (bf16*)((char*)d_ws + BF_BASE);
    bf16* ekws = qws2 + (size_t)QC * NP;
    bf16* vws  = ekws + (size_t)KC * NP;
    // ws usage: 65536 + (64+16+32)*524288*2 bytes ≈ 117.5 MB

    k_detect<<<1, 64, 0, stream>>>((const unsigned short*)d_in[0], flag);
    k_prep<<<1, 256, 0, stream>>>(d_in[1], d_in[2], d_in[3], d_in[4], d_in[5],
                                  d_in[6], d_in[7], d_in[8], d_in[9], wf, flag);
    k_qkv<<<NP / 128, 256, 0, stream>>>(d_in[0], wf, flag, qws2, ekws, vws);
    k_lamc<<<dim3(NN / LCHUNK, BB), 256, 0, stream>>>(ekws, vws, wf + S_OFF, wf + M_OFF);
    k_out<<<dim3(2 * HH, BB), 256, 0, stream>>>(qws2, vws, wf, wf + S_OFF, wf + M_OFF,
                                                flag, d_out);
}